// Round 5
// baseline (139.395 us; speedup 1.0000x reference)
//
#include <hip/hip_runtime.h>

#define HW 256
#define CH 64

// 16-lane (DPP row) rotate-and-add; CTRL = 0x120 | n  (row_ror:n)
template <int CTRL>
__device__ __forceinline__ float row_rot_add(float v) {
    int r = __builtin_amdgcn_update_dpp(0, __float_as_int(v), CTRL, 0xf, 0xf, false);
    return v + __int_as_float(r);
}

// Compute the packed sample element-offset for (pixel p, tap) per reference
// semantics; returns element offset into the batch image, or -1 if the
// sample lands on the zero-pad ring.
__device__ __forceinline__ int tap_pack(const float* __restrict__ gt,
                                        const float* __restrict__ off,
                                        int p, int i, int j, int tap) {
    int ky = tap / 3, kx = tap - ky * 3;
    int iy = i + ky - 1, ix = j + kx - 1;
    bool interior = (iy >= 0) & (iy < HW) & (ix >= 0) & (ix < HW);
    int yi = interior ? iy : 0;
    int xi = interior ? ix : 0;

    float p_mask = (yi >= 1 && xi >= 1) ? gt[(yi - 1) * HW + (xi - 1)] : 0.f;

    float2 o2 = *(const float2*)(off + (long)p * 18 + 2 * tap);
    float yf = (float)yi, xf = (float)xi;

    float yof = fminf(fmaxf(floorf(yf + o2.x), 0.f), 257.f);
    float xof = fminf(fmaxf(floorf(xf + o2.y), 0.f), 257.f);
    int yo = (int)yof, xo = (int)xof;
    float p_mask_off = (yo >= 1 && yo <= HW && xo >= 1 && xo <= HW)
                       ? gt[(yo - 1) * HW + (xo - 1)] : 0.f;
    float diff = (p_mask != p_mask_off) ? 1.f : 0.f;

    float y = fminf(fmaxf(yf + o2.x * diff, 0.f), 255.f);
    float x = fminf(fmaxf(xf + o2.y * diff, 0.f), 255.f);
    int y0 = (int)y, x0 = (int)x;

    bool valid = (y0 >= 1) & (x0 >= 1);
    int eoff = ((y0 - 1) * HW + (x0 - 1)) * CH;
    return valid ? eoff : -1;
}

// 256 threads = 4 waves; each wave handles 8 pixels in two sets of 4
// (16 lanes/pixel: lane%16 = channel quad). Phase1: lanes t<9 compute one
// tap address per (set,pixel); handoff via LDS broadcast. Phase3: all 18
// float4 gathers issued before a compiler fence (kept in flight). Phase4:
// FMA vs LDS weights, DPP-rotate reduce, store.
__global__ __launch_bounds__(256, 4) void DeformableConvLayer_kernel(
    const float* __restrict__ inp,    // [4,256,256,64]
    const float* __restrict__ gt,     // [256,256]
    const float* __restrict__ off,    // [4,256,256,18]
    const float* __restrict__ ker,    // [9][64]
    const float* __restrict__ bias,   // [1]
    float* __restrict__ out)          // [4,256,256]
{
    __shared__ float wlds[576];            // 9 taps x 64 ch
    __shared__ int   pklds[4][2][4][12];   // [wave][set][group][tap(pad 12)]

    const int tid = threadIdx.x;
    if (tid < 144) ((float4*)wlds)[tid] = ((const float4*)ker)[tid];

    const int lane = tid & 63;
    const int wave = tid >> 6;
    const int q    = lane >> 4;       // pixel-in-set 0..3
    const int t    = lane & 15;       // channel quad 0..15

    // XCD swizzle: 8192 blocks -> contiguous 1024-block chunk per XCD
    const int bid = blockIdx.x;
    const int vb  = (bid & 7) * 1024 + (bid >> 3);

    const int base = vb * 32 + wave * 8;   // 8 consecutive pixels per wave
    const int pA = base + q;
    const int pB = base + 4 + q;
    const int b  = base >> 16;             // uniform per block
    const float* inb = inp + (long)b * (HW * HW * CH);

    // ---- Phase 1: one tap per lane for both pixel sets ----
    if (t < 9) {
        int iA = (pA >> 8) & 255, jA = pA & 255;
        int iB = (pB >> 8) & 255, jB = pB & 255;
        pklds[wave][0][q][t] = tap_pack(gt, off, pA, iA, jA, t);
        pklds[wave][1][q][t] = tap_pack(gt, off, pB, iB, jB, t);
    }
    __syncthreads();   // covers wlds staging + pk handoff

    // ---- Phase 2: broadcast-read tap addresses (conflict-free LDS) ----
    int pkA[9], pkB[9];
    #pragma unroll
    for (int k = 0; k < 9; ++k) pkA[k] = pklds[wave][0][q][k];
    #pragma unroll
    for (int k = 0; k < 9; ++k) pkB[k] = pklds[wave][1][q][k];

    // ---- Phase 3: 18 independent gathers, all issued before the fence ----
    float4 vA[9], vB[9];
    #pragma unroll
    for (int k = 0; k < 9; ++k) {
        int eo = pkA[k] >= 0 ? pkA[k] : 0;
        vA[k] = *(const float4*)(inb + eo + t * 4);
    }
    #pragma unroll
    for (int k = 0; k < 9; ++k) {
        int eo = pkB[k] >= 0 ? pkB[k] : 0;
        vB[k] = *(const float4*)(inb + eo + t * 4);
    }
    asm volatile("" ::: "memory");   // keep all 18 loads in flight

    // ---- Phase 4: FMA + DPP reduce ----
    float accA = 0.f, accB = 0.f;
    #pragma unroll
    for (int k = 0; k < 9; ++k) {
        float4 w = ((const float4*)wlds)[k * 16 + t];
        float dA = vA[k].x * w.x + vA[k].y * w.y + vA[k].z * w.z + vA[k].w * w.w;
        float dB = vB[k].x * w.x + vB[k].y * w.y + vB[k].z * w.z + vB[k].w * w.w;
        accA = fmaf(pkA[k] >= 0 ? 1.f : 0.f, dA, accA);
        accB = fmaf(pkB[k] >= 0 ? 1.f : 0.f, dB, accB);
    }

    accA = row_rot_add<0x128>(accA);   // ror 8
    accA = row_rot_add<0x124>(accA);   // ror 4
    accA = row_rot_add<0x122>(accA);   // ror 2
    accA = row_rot_add<0x121>(accA);   // ror 1
    accB = row_rot_add<0x128>(accB);
    accB = row_rot_add<0x124>(accB);
    accB = row_rot_add<0x122>(accB);
    accB = row_rot_add<0x121>(accB);

    if (t == 0) {
        float bs = bias[0];
        out[pA] = accA + bs;
        out[pB] = accB + bs;
    }
}

extern "C" void kernel_launch(void* const* d_in, const int* in_sizes, int n_in,
                              void* d_out, int out_size, void* d_ws, size_t ws_size,
                              hipStream_t stream) {
    const float* inp  = (const float*)d_in[0];
    const float* gt   = (const float*)d_in[1];
    const float* off  = (const float*)d_in[2];
    const float* ker  = (const float*)d_in[3];
    const float* bias = (const float*)d_in[4];
    float* out = (float*)d_out;

    // 262144 pixels / 32 per block = 8192 blocks
    DeformableConvLayer_kernel<<<8192, 256, 0, stream>>>(inp, gt, off, ker, bias, out);
}

// Round 6
// 134.251 us; speedup vs baseline: 1.0383x; 1.0383x over previous
//
#include <hip/hip_runtime.h>

#define HW 256
#define CH 64
#define NG 8            // pixel-groups (4 px each) per wave
#define NPX (NG * 4)    // 32 px per wave
#define LASTP 262143

// 16-lane (DPP row) rotate-and-add; CTRL = 0x120 | n  (row_ror:n)
template <int CTRL>
__device__ __forceinline__ float row_rot_add(float v) {
    int r = __builtin_amdgcn_update_dpp(0, __float_as_int(v), CTRL, 0xf, 0xf, false);
    return v + __int_as_float(r);
}

// 256 threads = 4 waves, each wave independent: 32 consecutive pixels in a
// 4-stage software pipeline (S1 offsets -> S2 mask gathers -> S3 input
// gathers -> S4 FMA/reduce/store), regions pinned by sched_barrier(0).
__global__ __launch_bounds__(256, 3) void DeformableConvLayer_kernel(
    const float* __restrict__ inp,    // [4,256,256,64]
    const float* __restrict__ gt,     // [256,256]
    const float* __restrict__ off,    // [4,256,256,18]
    const float* __restrict__ ker,    // [9][64]
    const float* __restrict__ bias,   // [1]
    float* __restrict__ out)          // [4,256,256]
{
    const int tid  = threadIdx.x;
    const int lane = tid & 63;
    const int wave = tid >> 6;
    const int q    = lane >> 4;          // pixel-in-group 0..3
    const int t    = lane & 15;          // channel quad 0..15
    const int tp   = t < 9 ? t : 8;      // tap id for coord lanes (clamped)
    const int ky   = tp / 3, kx = tp - ky * 3;
    const int grpbase = lane & 48;       // q*16

    // XCD swizzle: 2048 blocks -> 256 contiguous blocks per XCD
    const int bid = blockIdx.x;
    const int vb  = (bid & 7) * 256 + (bid >> 3);
    const int wbase = (vb * 4 + wave) * NPX;
    const int b = wbase >> 16;
    const float* inb = inp + (long)b * (HW * HW * CH);
    const float bs = bias[0];

    // weights resident in VGPRs: 9 taps x this lane's channel quad
    float4 w[9];
    #pragma unroll
    for (int k = 0; k < 9; ++k)
        w[k] = *(const float4*)(ker + k * CH + t * 4);

    // ---- pipeline state, double-buffered (period-2 lifetimes) ----
    float o2y[2], o2x[2];
    float pmask[2], pmoff[2], cy[2], cx[2], yfb[2], xfb[2];
    float4 v[2][9];
    int smask[2];

    // S1: issue offset load for group gg
    auto S1 = [&](int gg, int B) {
        int p = wbase + gg * 4 + q; p = p > LASTP ? LASTP : p;
        float2 o = *(const float2*)(off + (long)p * 18 + 2 * tp);
        o2y[B] = o.x; o2x[B] = o.y;
    };

    // S2: consume offsets, issue both mask gathers, compute candidates
    auto S2 = [&](int gg, int B) {
        int p = wbase + gg * 4 + q; p = p > LASTP ? LASTP : p;
        int i = (p >> 8) & 255, j = p & 255;
        int iy = i + ky - 1, ix = j + kx - 1;
        bool interior = (iy >= 0) & (iy < HW) & (ix >= 0) & (ix < HW);
        int yi = interior ? iy : 0;
        int xi = interior ? ix : 0;
        float yf = (float)yi, xf = (float)xi;
        yfb[B] = yf; xfb[B] = xf;
        pmask[B] = (yi >= 1 && xi >= 1) ? gt[(yi - 1) * HW + (xi - 1)] : 0.f;
        float oy = o2y[B], ox = o2x[B];
        float yof = fminf(fmaxf(floorf(yf + oy), 0.f), 257.f);
        float xof = fminf(fmaxf(floorf(xf + ox), 0.f), 257.f);
        int yo = (int)yof, xo = (int)xof;
        pmoff[B] = (yo >= 1 && yo <= HW && xo >= 1 && xo <= HW)
                   ? gt[(yo - 1) * HW + (xo - 1)] : 0.f;
        cy[B] = fminf(fmaxf(yf + oy, 0.f), 255.f);
        cx[B] = fminf(fmaxf(xf + ox, 0.f), 255.f);
    };

    // S3: consume masks, final coords, broadcast, issue 9 input gathers
    auto S3 = [&](int gg, int B) {
        bool diff = (pmask[B] != pmoff[B]);
        float y = diff ? cy[B] : yfb[B];
        float x = diff ? cx[B] : xfb[B];
        int y0 = (int)y, x0 = (int)x;
        bool valid = (y0 >= 1) & (x0 >= 1);
        int pack = valid ? ((y0 - 1) * HW + (x0 - 1)) * CH : -1;
        int m = 0;
        #pragma unroll
        for (int k = 0; k < 9; ++k) {
            int pk = __shfl(pack, grpbase + k);
            m |= (pk >= 0 ? 1 : 0) << k;
            int eo = pk >= 0 ? pk : 0;
            v[B][k] = *(const float4*)(inb + eo + t * 4);
        }
        smask[B] = m;
    };

    // S4: consume gathers, FMA, DPP reduce, store
    auto S4 = [&](int gg, int B) {
        float acc = 0.f;
        int m = smask[B];
        #pragma unroll
        for (int k = 0; k < 9; ++k) {
            float4 vv = v[B][k];
            float d = vv.x * w[k].x + vv.y * w[k].y + vv.z * w[k].z + vv.w * w[k].w;
            float s = (float)((m >> k) & 1);
            acc = fmaf(s, d, acc);
        }
        acc = row_rot_add<0x128>(acc);
        acc = row_rot_add<0x124>(acc);
        acc = row_rot_add<0x122>(acc);
        acc = row_rot_add<0x121>(acc);
        if (t == 0) out[wbase + gg * 4 + q] = acc + bs;
    };

    // ---- prologue ----
    S1(0, 0);
    __builtin_amdgcn_sched_barrier(0);
    S1(1, 1); S2(0, 0);
    __builtin_amdgcn_sched_barrier(0);
    S1(2, 0); S2(1, 1); S3(0, 0);
    __builtin_amdgcn_sched_barrier(0);

    // ---- steady state (tail prefetches clamp to valid pixels, harmless) ----
    #pragma unroll
    for (int n = 0; n < NG; n += 2) {
        S1(n + 3, 1); S2(n + 2, 0); S3(n + 1, 1); S4(n, 0);
        __builtin_amdgcn_sched_barrier(0);
        S1(n + 4, 0); S2(n + 3, 1); S3(n + 2, 0); S4(n + 1, 1);
        __builtin_amdgcn_sched_barrier(0);
    }
}

extern "C" void kernel_launch(void* const* d_in, const int* in_sizes, int n_in,
                              void* d_out, int out_size, void* d_ws, size_t ws_size,
                              hipStream_t stream) {
    const float* inp  = (const float*)d_in[0];
    const float* gt   = (const float*)d_in[1];
    const float* off  = (const float*)d_in[2];
    const float* ker  = (const float*)d_in[3];
    const float* bias = (const float*)d_in[4];
    float* out = (float*)d_out;

    // 262144 px / 32 px-per-wave / 4 waves = 2048 blocks
    DeformableConvLayer_kernel<<<2048, 256, 0, stream>>>(inp, gt, off, ker, bias, out);
}